// Round 11
// baseline (211.421 us; speedup 1.0000x reference)
//
#include <hip/hip_runtime.h>
#include <hip/hip_bf16.h>
#include <math.h>

#define B   2
#define TQ  1024
#define TKV 1024
#define D   1024
#define H   16
#define HD  64
#define P   64     // 2*SPAN
#define SPAN 32

#define NEG_INF (-3.0e38f)

typedef __attribute__((ext_vector_type(8))) short bf16x8;
typedef __attribute__((ext_vector_type(4))) float f32x4;
typedef unsigned short ushort_t;

// ---------------- workspace layout ----------------
// f32 region (float offsets):
static constexpr size_t RE_OFF   = 0;                          // 64K floats
static constexpr size_t POSK_OFF = (size_t)64 * 1024;
static constexpr size_t POSQ_OFF = (size_t)128 * 1024;
static constexpr size_t FLOATS_END = (size_t)192 * 1024;
static constexpr size_t SHORT_BASE_BYTES = FLOATS_END * 4;     // 768 KB
// ushort region (ushort offsets from SHORT_BASE), each buffer 2M elems = 4MB:
static constexpr size_t C2P_S  = 0;
static constexpr size_t P2C_S  = (size_t)2 * 1024 * 1024;
static constexpr size_t QH_S   = (size_t)4 * 1024 * 1024;
static constexpr size_t QL_S   = (size_t)6 * 1024 * 1024;
static constexpr size_t KH_S   = (size_t)8 * 1024 * 1024;
static constexpr size_t KL_S   = (size_t)10 * 1024 * 1024;
static constexpr size_t VTH_S  = (size_t)12 * 1024 * 1024;
static constexpr size_t VTL_S  = (size_t)14 * 1024 * 1024;
static constexpr size_t CTXH_S = (size_t)16 * 1024 * 1024;     // partial half1 -> final ctx
static constexpr size_t CTXL_S = (size_t)18 * 1024 * 1024;
static constexpr size_t AKVH_S = (size_t)20 * 1024 * 1024;     // pre-split kv; later partial half0
static constexpr size_t AKVL_S = (size_t)22 * 1024 * 1024;
static constexpr size_t TAB_OFF_BYTES = SHORT_BASE_BYTES + (size_t)24 * 1024 * 1024 * 2;
static constexpr size_t PML_OFF_BYTES = TAB_OFF_BYTES + 4096;  // 2 half x 32768 rows x (m,l) f32

// split x into hi (bit-truncated bf16) + lo (RN bf16 of exact residual)
__device__ __forceinline__ void split2(float x, unsigned short& h, unsigned short& l) {
  unsigned int u = __float_as_uint(x);
  h = (unsigned short)(u >> 16);
  float r = x - __uint_as_float(u & 0xffff0000u);   // exact
  unsigned int v = __float_as_uint(r);
  v += 0x7fffu + ((v >> 16) & 1u);                  // RN-even
  l = (unsigned short)(v >> 16);
}

__device__ __forceinline__ unsigned short bf16rn(float x) {
  unsigned int v = __float_as_uint(x);
  v += 0x7fffu + ((v >> 16) & 1u);
  return (unsigned short)(v >> 16);
}

__device__ __forceinline__ float bf2f(unsigned short u) {
  return __uint_as_float(((unsigned int)u) << 16);
}

// ---------------- pre-split kv (2M floats) into bf16 hi/lo ----------------
__global__ __launch_bounds__(256) void presplit_kernel(const float* __restrict__ in,
    ushort_t* __restrict__ oh, ushort_t* __restrict__ ol) {
  size_t i = ((size_t)blockIdx.x * 256 + threadIdx.x) * 8;
  float4 a = *(const float4*)&in[i];
  float4 b = *(const float4*)&in[i + 4];
  float xs[8] = {a.x, a.y, a.z, a.w, b.x, b.y, b.z, b.w};
  bf16x8 th, tl;
  #pragma unroll
  for (int j = 0; j < 8; j++) {
    unsigned short hh, ll;
    split2(xs[j], hh, ll);
    th[j] = (short)hh; tl[j] = (short)ll;
  }
  *(bf16x8*)&oh[i] = th;
  *(bf16x8*)&ol[i] = tl;
}

// ---------------- LayerNorm over rel_emb rows ----------------
__global__ __launch_bounds__(256) void ln_kernel(const float* __restrict__ x,
    const float* __restrict__ g, const float* __restrict__ bta, float* __restrict__ out) {
  const int row = blockIdx.x;
  const float* xr = x + (size_t)row * D;
  const int tid = threadIdx.x;
  __shared__ float red[4];
  float s = 0.f;
  for (int i = tid; i < D; i += 256) s += xr[i];
  #pragma unroll
  for (int off = 32; off; off >>= 1) s += __shfl_down(s, off);
  if ((tid & 63) == 0) red[tid >> 6] = s;
  __syncthreads();
  float mu = (red[0] + red[1] + red[2] + red[3]) * (1.0f / D);
  __syncthreads();
  float vs = 0.f;
  for (int i = tid; i < D; i += 256) { float dd = xr[i] - mu; vs += dd * dd; }
  #pragma unroll
  for (int off = 32; off; off >>= 1) vs += __shfl_down(vs, off);
  if ((tid & 63) == 0) red[tid >> 6] = vs;
  __syncthreads();
  float var = (red[0] + red[1] + red[2] + red[3]) * (1.0f / D);
  float rs = rsqrtf(var + 1e-5f);
  for (int i = tid; i < D; i += 256)
    out[(size_t)row * D + i] = (xr[i] - mu) * rs * g[i] + bta[i];
}

// ---------------- log-bucket position table ----------------
__global__ void tab_kernel(unsigned char* __restrict__ tab) {
  int i = blockIdx.x * 256 + threadIdx.x;
  if (i >= 2047) return;
  int d = i - 1023;
  int ad = d < 0 ? -d : d;
  int bucket;
  if (ad <= 16) {
    bucket = d;
  } else {
    double x = log((double)ad / 16.0) / log(127.0 / 16.0) * 15.0;
    double xr = floor(x + 0.5);
    double xc = (fabs(x - xr) < 1e-9) ? xr : ceil(x);
    int li = (int)xc + 16;
    bucket = (d > 0) ? li : -li;
  }
  int t = bucket + SPAN;
  t = t < 0 ? 0 : (t > 63 ? 63 : t);
  tab[i] = (unsigned char)t;
}

// ---------------- MFMA split-bf16 pos projections: C[64,1024] = re @ W^T + b ----------------
__global__ __launch_bounds__(256) void gemm_pos(const float* __restrict__ A,
    const float* __restrict__ W0, const float* __restrict__ b0, float* __restrict__ C0,
    const float* __restrict__ W1, const float* __restrict__ b1, float* __restrict__ C1) {
  const float* W = blockIdx.z ? W1 : W0;
  const float* bias = blockIdx.z ? b1 : b0;
  float* C = blockIdx.z ? C1 : C0;

  __shared__ short sAh[64 * 32], sAl[64 * 32], sBh[64 * 32], sBl[64 * 32];
  const int t = threadIdx.x;
  const int bn = blockIdx.x * 64;
  const int wid = t >> 6, lane = t & 63;
  const int wr = wid >> 1, wc = wid & 1;
  const int fr = lane & 15, fo = (lane >> 4) * 8;
  const int srow = t >> 3, scol = (t & 7) * 4;

  f32x4 acc[2][2];
  #pragma unroll
  for (int i = 0; i < 2; i++)
    #pragma unroll
    for (int j = 0; j < 2; j++) acc[i][j] = (f32x4){0.f, 0.f, 0.f, 0.f};

  float4 rA[2], rW[2];
  auto ld = [&](int k0) {
    #pragma unroll
    for (int i = 0; i < 2; i++) {
      rA[i] = *(const float4*)&A[(size_t)(srow + 32 * i) * 1024 + k0 + scol];
      rW[i] = *(const float4*)&W[(size_t)(bn + srow + 32 * i) * 1024 + k0 + scol];
    }
  };
  ld(0);

  for (int k0 = 0; k0 < 1024; k0 += 32) {
    __syncthreads();
    #pragma unroll
    for (int i = 0; i < 2; i++) {
      int row = srow + 32 * i;
      unsigned short h0,h1,h2,h3,l0,l1,l2,l3;
      split2(rA[i].x,h0,l0); split2(rA[i].y,h1,l1); split2(rA[i].z,h2,l2); split2(rA[i].w,h3,l3);
      *(short4*)&sAh[row * 32 + scol] = make_short4((short)h0,(short)h1,(short)h2,(short)h3);
      *(short4*)&sAl[row * 32 + scol] = make_short4((short)l0,(short)l1,(short)l2,(short)l3);
      split2(rW[i].x,h0,l0); split2(rW[i].y,h1,l1); split2(rW[i].z,h2,l2); split2(rW[i].w,h3,l3);
      *(short4*)&sBh[row * 32 + scol] = make_short4((short)h0,(short)h1,(short)h2,(short)h3);
      *(short4*)&sBl[row * 32 + scol] = make_short4((short)l0,(short)l1,(short)l2,(short)l3);
    }
    if (k0 + 32 < 1024) ld(k0 + 32);
    __syncthreads();

    bf16x8 ah[2], al[2], bh[2], bl[2];
    #pragma unroll
    for (int mf = 0; mf < 2; mf++) {
      int r = (wr * 32 + mf * 16 + fr) * 32 + fo;
      ah[mf] = *(const bf16x8*)&sAh[r];
      al[mf] = *(const bf16x8*)&sAl[r];
    }
    #pragma unroll
    for (int nf = 0; nf < 2; nf++) {
      int r = (wc * 32 + nf * 16 + fr) * 32 + fo;
      bh[nf] = *(const bf16x8*)&sBh[r];
      bl[nf] = *(const bf16x8*)&sBl[r];
    }
    #pragma unroll
    for (int mf = 0; mf < 2; mf++)
      #pragma unroll
      for (int nf = 0; nf < 2; nf++) {
        acc[mf][nf] = __builtin_amdgcn_mfma_f32_16x16x32_bf16(ah[mf], bh[nf], acc[mf][nf], 0, 0, 0);
        acc[mf][nf] = __builtin_amdgcn_mfma_f32_16x16x32_bf16(ah[mf], bl[nf], acc[mf][nf], 0, 0, 0);
        acc[mf][nf] = __builtin_amdgcn_mfma_f32_16x16x32_bf16(al[mf], bh[nf], acc[mf][nf], 0, 0, 0);
      }
  }

  #pragma unroll
  for (int mf = 0; mf < 2; mf++) {
    int rbase = wr * 32 + mf * 16 + (lane >> 4) * 4;
    #pragma unroll
    for (int nf = 0; nf < 2; nf++) {
      int col = bn + wc * 32 + nf * 16 + fr;
      float bb = bias[col];
      #pragma unroll
      for (int r = 0; r < 4; r++)
        C[(size_t)(rbase + r) * 1024 + col] = acc[mf][nf][r] + bb;
    }
  }
}

// ---------------- split-bf16 MFMA GEMM (QKV): BM=128, BN=64, BK=32 ----------------
__global__ __launch_bounds__(256) void gemm_split(
    const float* __restrict__ Aq,
    const ushort_t* __restrict__ AKVH, const ushort_t* __restrict__ AKVL,
    const float* __restrict__ W0, const float* __restrict__ W1, const float* __restrict__ W2,
    const float* __restrict__ b0, const float* __restrict__ b1, const float* __restrict__ b2,
    ushort_t* __restrict__ QH_, ushort_t* __restrict__ QL_,
    ushort_t* __restrict__ KH_, ushort_t* __restrict__ KL_,
    ushort_t* __restrict__ VH_, ushort_t* __restrict__ VL_,
    int K) {
  const int z = blockIdx.z;
  const float* W = (z == 0) ? W0 : (z == 1) ? W1 : W2;
  const float* bias = (z == 0) ? b0 : (z == 1) ? b1 : b2;

  const int flat2 = blockIdx.y * 16 + blockIdx.x;
  const int nid = (flat2 & 7) * 32 + (flat2 >> 3);
  const int bn = (nid & 15) * 64;
  const int bm = (nid >> 4) * 128;

  __shared__ short sAhi[128 * 32];
  __shared__ short sAlo[128 * 32];
  __shared__ short sBhi[64 * 32];
  __shared__ short sBlo[64 * 32];

  const int t = threadIdx.x;
  const int wid = t >> 6, lane = t & 63;
  const int wr = wid >> 1, wc = wid & 1;
  const int fr = lane & 15, fo = (lane >> 4) * 8;

  f32x4 acc[4][2];
  #pragma unroll
  for (int i = 0; i < 4; i++)
    #pragma unroll
    for (int j = 0; j < 2; j++)
      acc[i][j] = (f32x4){0.f, 0.f, 0.f, 0.f};

  const int srow = t >> 3;
  const int scol = (t & 7) * 4;
  const int ar = t >> 1;
  const int ac = (t & 1) * 16;

  float4 rA[4], rW[2];
  bf16x8 rAH[2], rAL[2];
  auto ld = [&](int k0) {
    if (z == 0) {
      #pragma unroll
      for (int i = 0; i < 4; i++)
        rA[i] = *(const float4*)&Aq[(size_t)(bm + srow + 32 * i) * K + k0 + scol];
    } else {
      const size_t abase = (size_t)(bm + ar) * K + k0 + ac;
      rAH[0] = *(const bf16x8*)&AKVH[abase];
      rAH[1] = *(const bf16x8*)&AKVH[abase + 8];
      rAL[0] = *(const bf16x8*)&AKVL[abase];
      rAL[1] = *(const bf16x8*)&AKVL[abase + 8];
    }
    #pragma unroll
    for (int i = 0; i < 2; i++)
      rW[i] = *(const float4*)&W[(size_t)(bn + srow + 32 * i) * K + k0 + scol];
  };
  ld(0);

  for (int k0 = 0; k0 < K; k0 += 32) {
    __syncthreads();
    if (z == 0) {
      #pragma unroll
      for (int i = 0; i < 4; i++) {
        int row = srow + 32 * i;
        unsigned short h0, h1, h2, h3, l0, l1, l2, l3;
        split2(rA[i].x, h0, l0); split2(rA[i].y, h1, l1); split2(rA[i].z, h2, l2); split2(rA[i].w, h3, l3);
        *(short4*)&sAhi[row * 32 + scol] = make_short4((short)h0, (short)h1, (short)h2, (short)h3);
        *(short4*)&sAlo[row * 32 + scol] = make_short4((short)l0, (short)l1, (short)l2, (short)l3);
      }
    } else {
      *(bf16x8*)&sAhi[ar * 32 + ac]     = rAH[0];
      *(bf16x8*)&sAhi[ar * 32 + ac + 8] = rAH[1];
      *(bf16x8*)&sAlo[ar * 32 + ac]     = rAL[0];
      *(bf16x8*)&sAlo[ar * 32 + ac + 8] = rAL[1];
    }
    #pragma unroll
    for (int i = 0; i < 2; i++) {
      int row = srow + 32 * i;
      unsigned short h0, h1, h2, h3, l0, l1, l2, l3;
      split2(rW[i].x, h0, l0); split2(rW[i].y, h1, l1); split2(rW[i].z, h2, l2); split2(rW[i].w, h3, l3);
      *(short4*)&sBhi[row * 32 + scol] = make_short4((short)h0, (short)h1, (short)h2, (short)h3);
      *(short4*)&sBlo[row * 32 + scol] = make_short4((short)l0, (short)l1, (short)l2, (short)l3);
    }
    if (k0 + 32 < K) ld(k0 + 32);
    __syncthreads();

    bf16x8 ah[4], al[4], bh[2], bl[2];
    #pragma unroll
    for (int mf = 0; mf < 4; mf++) {
      int r = (wr * 64 + mf * 16 + fr) * 32 + fo;
      ah[mf] = *(const bf16x8*)&sAhi[r];
      al[mf] = *(const bf16x8*)&sAlo[r];
    }
    #pragma unroll
    for (int nf = 0; nf < 2; nf++) {
      int r = (wc * 32 + nf * 16 + fr) * 32 + fo;
      bh[nf] = *(const bf16x8*)&sBhi[r];
      bl[nf] = *(const bf16x8*)&sBlo[r];
    }
    #pragma unroll
    for (int mf = 0; mf < 4; mf++)
      #pragma unroll
      for (int nf = 0; nf < 2; nf++) {
        acc[mf][nf] = __builtin_amdgcn_mfma_f32_16x16x32_bf16(ah[mf], bh[nf], acc[mf][nf], 0, 0, 0);
        acc[mf][nf] = __builtin_amdgcn_mfma_f32_16x16x32_bf16(ah[mf], bl[nf], acc[mf][nf], 0, 0, 0);
        acc[mf][nf] = __builtin_amdgcn_mfma_f32_16x16x32_bf16(al[mf], bh[nf], acc[mf][nf], 0, 0, 0);
      }
  }

  if (z == 2) {
    #pragma unroll
    for (int mf = 0; mf < 4; mf++) {
      int m0 = bm + wr * 64 + mf * 16 + (lane >> 4) * 4;
      int bb2 = m0 >> 10, t0 = m0 & 1023;
      #pragma unroll
      for (int nf = 0; nf < 2; nf++) {
        int col = bn + wc * 32 + nf * 16 + fr;
        int hh = col >> 6, dd = col & 63;
        float bvv = bias[col];
        unsigned short h4[4], l4[4];
        #pragma unroll
        for (int r = 0; r < 4; r++) split2(acc[mf][nf][r] + bvv, h4[r], l4[r]);
        size_t dst = (((size_t)bb2 * 16 + hh) * 64 + dd) * 1024 + t0;
        *(short4*)&VH_[dst] = make_short4((short)h4[0], (short)h4[1], (short)h4[2], (short)h4[3]);
        *(short4*)&VL_[dst] = make_short4((short)l4[0], (short)l4[1], (short)l4[2], (short)l4[3]);
      }
    }
  } else {
    ushort_t* OH = (z == 0) ? QH_ : KH_;
    ushort_t* OL = (z == 0) ? QL_ : KL_;
    #pragma unroll
    for (int mf = 0; mf < 4; mf++) {
      int rbase = bm + wr * 64 + mf * 16 + (lane >> 4) * 4;
      #pragma unroll
      for (int nf = 0; nf < 2; nf++) {
        int col = bn + wc * 32 + nf * 16 + fr;
        float bb = bias[col];
        #pragma unroll
        for (int r = 0; r < 4; r++) {
          unsigned short hh, ll;
          split2(acc[mf][nf][r] + bb, hh, ll);
          OH[(size_t)(rbase + r) * 1024 + col] = hh;
          OL[(size_t)(rbase + r) * 1024 + col] = ll;
        }
      }
    }
  }
}

// ---------------- out projection: C[2048,1024] = ctx(hi/lo bf16) @ Wo^T + bo ----------------
__global__ __launch_bounds__(256) void gemm_out(
    const ushort_t* __restrict__ AH, const ushort_t* __restrict__ AL,
    const float* __restrict__ W, const float* __restrict__ bias, float* __restrict__ C) {
  __shared__ short sAh[64 * 32], sAl[64 * 32], sBh[64 * 32], sBl[64 * 32];
  const int t = threadIdx.x;
  const int flat2 = blockIdx.y * 16 + blockIdx.x;
  const int nid = (flat2 & 7) * 64 + (flat2 >> 3);
  const int bn = (nid & 15) * 64;
  const int bm = (nid >> 4) * 64;
  const int wid = t >> 6, lane = t & 63;
  const int wr = wid >> 1, wc = wid & 1;
  const int fr = lane & 15, fo = (lane >> 4) * 8;
  const int arow = t >> 2, achk = (t & 3) * 8;
  const int srow = t >> 3, scol = (t & 7) * 4;

  f32x4 acc[2][2];
  #pragma unroll
  for (int i = 0; i < 2; i++)
    #pragma unroll
    for (int j = 0; j < 2; j++) acc[i][j] = (f32x4){0.f, 0.f, 0.f, 0.f};

  bf16x8 rAH, rAL;
  float4 rW[2];
  auto ld = [&](int k0) {
    rAH = *(const bf16x8*)&AH[(size_t)(bm + arow) * 1024 + k0 + achk];
    rAL = *(const bf16x8*)&AL[(size_t)(bm + arow) * 1024 + k0 + achk];
    #pragma unroll
    for (int i = 0; i < 2; i++)
      rW[i] = *(const float4*)&W[(size_t)(bn + srow + 32 * i) * 1024 + k0 + scol];
  };
  ld(0);

  for (int k0 = 0; k0 < 1024; k0 += 32) {
    __syncthreads();
    *(bf16x8*)&sAh[arow * 32 + achk] = rAH;
    *(bf16x8*)&sAl[arow * 32 + achk] = rAL;
    #pragma unroll
    for (int i = 0; i < 2; i++) {
      int row = srow + 32 * i;
      unsigned short h0,h1,h2,h3,l0,l1,l2,l3;
      split2(rW[i].x,h0,l0); split2(rW[i].y,h1,l1); split2(rW[i].z,h2,l2); split2(rW[i].w,h3,l3);
      *(short4*)&sBh[row * 32 + scol] = make_short4((short)h0,(short)h1,(short)h2,(short)h3);
      *(short4*)&sBl[row * 32 + scol] = make_short4((short)l0,(short)l1,(short)l2,(short)l3);
    }
    if (k0 + 32 < 1024) ld(k0 + 32);
    __syncthreads();

    bf16x8 ah[2], al[2], bh[2], bl[2];
    #pragma unroll
    for (int mf = 0; mf < 2; mf++) {
      int r = (wr * 32 + mf * 16 + fr) * 32 + fo;
      ah[mf] = *(const bf16x8*)&sAh[r];
      al[mf] = *(const bf16x8*)&sAl[r];
    }
    #pragma unroll
    for (int nf = 0; nf < 2; nf++) {
      int r = (wc * 32 + nf * 16 + fr) * 32 + fo;
      bh[nf] = *(const bf16x8*)&sBh[r];
      bl[nf] = *(const bf16x8*)&sBl[r];
    }
    #pragma unroll
    for (int mf = 0; mf < 2; mf++)
      #pragma unroll
      for (int nf = 0; nf < 2; nf++) {
        acc[mf][nf] = __builtin_amdgcn_mfma_f32_16x16x32_bf16(ah[mf], bh[nf], acc[mf][nf], 0, 0, 0);
        acc[mf][nf] = __builtin_amdgcn_mfma_f32_16x16x32_bf16(ah[mf], bl[nf], acc[mf][nf], 0, 0, 0);
        acc[mf][nf] = __builtin_amdgcn_mfma_f32_16x16x32_bf16(al[mf], bh[nf], acc[mf][nf], 0, 0, 0);
      }
  }

  #pragma unroll
  for (int mf = 0; mf < 2; mf++) {
    int rbase = bm + wr * 32 + mf * 16 + (lane >> 4) * 4;
    #pragma unroll
    for (int nf = 0; nf < 2; nf++) {
      int col = bn + wc * 32 + nf * 16 + fr;
      float bb = bias[col];
      #pragma unroll
      for (int r = 0; r < 4; r++)
        C[(size_t)(rbase + r) * 1024 + col] = acc[mf][nf][r] + bb;
    }
  }
}

// ---------------- rel projection -> bf16 outputs pre-scaled by 1/sqrt(128) ----------------
__global__ __launch_bounds__(256) void relproj_kernel(
    const ushort_t* __restrict__ XH0, const ushort_t* __restrict__ XL0,
    const float* __restrict__ P0, ushort_t* __restrict__ O0,
    const ushort_t* __restrict__ XH1, const ushort_t* __restrict__ XL1,
    const float* __restrict__ P1, ushort_t* __restrict__ O1) {
  const int z = blockIdx.z;
  const ushort_t* XH = z ? XH1 : XH0;
  const ushort_t* XL = z ? XL1 : XL0;
  const float* POS = z ? P1 : P0;
  ushort_t* out = z ? O1 : O0;
  const int bh = blockIdx.y, b = bh >> 4, h = bh & 15;
  const int t0 = blockIdx.x * 64;
  __shared__ __align__(16) float sx[64][68];
  __shared__ __align__(16) float sp[64][68];
  const int tid = threadIdx.x;
  for (int i = tid; i < 4096; i += 256) {
    int r = i >> 6, d = i & 63;
    size_t idx = ((size_t)b * TQ + t0 + r) * D + h * HD + d;
    sx[d][r] = bf2f(XH[idx]) + bf2f(XL[idx]);
    sp[d][r] = POS[(size_t)r * D + h * HD + d];
  }
  __syncthreads();
  const int tx = tid & 15, ty = tid >> 4;
  float acc[4][4] = {};
  for (int d = 0; d < 64; d++) {
    float4 a4 = *(const float4*)&sx[d][ty * 4];
    float4 b4 = *(const float4*)&sp[d][tx * 4];
    float av[4] = {a4.x, a4.y, a4.z, a4.w};
    float bv[4] = {b4.x, b4.y, b4.z, b4.w};
    #pragma unroll
    for (int i = 0; i < 4; i++)
      #pragma unroll
      for (int j = 0; j < 4; j++)
        acc[i][j] += av[i] * bv[j];
  }
  const float inv_ps = 0.08838834764831845f;  // 1/sqrt(128)
  #pragma unroll
  for (int i = 0; i < 4; i++)
    #pragma unroll
    for (int j = 0; j < 4; j++)
      out[((size_t)bh * TQ + t0 + ty * 4 + i) * P + tx * 4 + j] = bf16rn(acc[i][j] * inv_ps);
}

// ---------------- MFMA flash attention, split-KV x2 (no-spin partials) ----------------
// grid 1024 (XCD-swizzled): nid -> (bh, q0, kvh). Each block does 8 KV tiles and writes
// RAW acc (bf16 hi/lo) + per-row (m,l); a separate merge kernel combines halves.
__global__ __launch_bounds__(256) void attn_mfma(
    const ushort_t* __restrict__ QHB, const ushort_t* __restrict__ QLB,
    const ushort_t* __restrict__ KH, const ushort_t* __restrict__ KL,
    const ushort_t* __restrict__ VTH, const ushort_t* __restrict__ VTL,
    const ushort_t* __restrict__ c2p, const ushort_t* __restrict__ p2c,
    const unsigned char* __restrict__ mask, const unsigned char* __restrict__ tab,
    ushort_t* __restrict__ P0H, ushort_t* __restrict__ P0L,
    ushort_t* __restrict__ P1H, ushort_t* __restrict__ P1L,
    float* __restrict__ pml) {
  const int flat = blockIdx.x;                       // 0..1023
  const int nid = (flat & 7) * 128 + (flat >> 3);    // bijective (1024 % 8 == 0)
  const int bh = nid >> 5, b = bh >> 4, h = bh & 15;
  const int q0 = ((nid >> 1) & 15) * 64;
  const int kvh = nid & 1;
  const int kt0 = kvh * 8, kt1 = kt0 + 8;

  const int tid = threadIdx.x;
  const int wid = tid >> 6, lane = tid & 63;
  const int g = lane >> 4, fr = lane & 15;

  __shared__ __align__(16) short sKh[4096], sKl[4096], sVh[4096], sVl[4096];
  __shared__ __align__(16) ushort_t sc2p[64][72];
  __shared__ __align__(16) ushort_t sp2c[64][72];
  __shared__ unsigned char stab[2048];
  __shared__ unsigned char smask[64];

  // --- Q fragments: direct bf16 hi/lo copies
  bf16x8 qh[2], ql[2];
  {
    const int qrow = q0 + wid * 16 + fr;
    const size_t qidx = ((size_t)b * TQ + qrow) * D + h * HD + g * 8;
    #pragma unroll
    for (int ks = 0; ks < 2; ks++) {
      qh[ks] = *(const bf16x8*)&QHB[qidx + ks * 32];
      ql[ks] = *(const bf16x8*)&QLB[qidx + ks * 32];
    }
  }

  const int sr = tid >> 2;
  const int sj0 = tid & 3;
  const int smf = sr >> 4, sfr = sr & 15;
  const int cb = (tid & 3) * 16;
  const int qloc = wid * 16 + fr;

  {
    const ushort_t* cp = c2p + ((size_t)bh * TQ + q0 + sr) * P + cb;
    *(bf16x8*)&sc2p[sr][cb]     = *(const bf16x8*)cp;
    *(bf16x8*)&sc2p[sr][cb + 8] = *(const bf16x8*)(cp + 8);
  }
  for (int i = tid; i < 2047; i += 256) stab[i] = tab[i];
  __syncthreads();
  const float c2p0  = bf2f(sc2p[qloc][0]);
  const float c2p63 = bf2f(sc2p[qloc][63]);

  f32x4 acc[4];
  #pragma unroll
  for (int nf = 0; nf < 4; nf++) acc[nf] = (f32x4){0.f, 0.f, 0.f, 0.f};
  float m_run = NEG_INF, l_run = 0.f;

  const float inv_s = 0.07216878364870323f;  // 1/sqrt(192)

  bf16x8 rKh[2], rKl[2], rVh[2], rVl[2], rP0, rP1;
  unsigned char rmask = 0;

  auto load_tile = [&](int kt) {
    const int k0n = kt * 64;
    const size_t kbase = ((size_t)b * TKV + k0n + sr) * D + h * HD;
    const size_t vbase = ((size_t)bh * HD + sr) * TKV + k0n;
    const ushort_t* pp = p2c + ((size_t)bh * TKV + k0n + sr) * P + cb;
    #pragma unroll
    for (int u = 0; u < 2; u++) {
      int jj = sj0 + u * 4;
      rKh[u] = *(const bf16x8*)(KH + kbase + jj * 8);
      rKl[u] = *(const bf16x8*)(KL + kbase + jj * 8);
      rVh[u] = *(const bf16x8*)(VTH + vbase + jj * 8);
      rVl[u] = *(const bf16x8*)(VTL + vbase + jj * 8);
    }
    rP0 = *(const bf16x8*)pp;
    rP1 = *(const bf16x8*)(pp + 8);
    if (tid < 64) rmask = mask[(size_t)b * TKV + k0n + tid];
  };

  load_tile(kt0);

  for (int kt = kt0; kt < kt1; kt++) {
    const int k0 = kt * 64;
    __syncthreads();
    #pragma unroll
    for (int u = 0; u < 2; u++) {
      int jj = sj0 + u * 4;
      int sub = smf * 8 + (jj >> 2) * 4 + (jj & 3);
      *(bf16x8*)&sKh[sub * 128 + sfr * 8] = rKh[u];
      *(bf16x8*)&sKl[sub * 128 + sfr * 8] = rKl[u];
      *(bf16x8*)&sVh[sub * 128 + sfr * 8] = rVh[u];
      *(bf16x8*)&sVl[sub * 128 + sfr * 8] = rVl[u];
    }
    *(bf16x8*)&sp2c[sr][cb]     = rP0;
    *(bf16x8*)&sp2c[sr][cb + 8] = rP1;
    if (tid < 64) smask[tid] = rmask;
    if (kt + 1 < kt1) load_tile(kt + 1);
    __syncthreads();

    f32x4 st[4];
    #pragma unroll
    for (int mf = 0; mf < 4; mf++) st[mf] = (f32x4){0.f, 0.f, 0.f, 0.f};
    __builtin_amdgcn_s_setprio(1);
    #pragma unroll
    for (int mf = 0; mf < 4; mf++) {
      #pragma unroll
      for (int ks = 0; ks < 2; ks++) {
        bf16x8 kh = *(const bf16x8*)&sKh[(mf * 8 + ks * 4 + g) * 128 + fr * 8];
        bf16x8 kl = *(const bf16x8*)&sKl[(mf * 8 + ks * 4 + g) * 128 + fr * 8];
        st[mf] = __builtin_amdgcn_mfma_f32_16x16x32_bf16(kh, qh[ks], st[mf], 0, 0, 0);
        st[mf] = __builtin_amdgcn_mfma_f32_16x16x32_bf16(kh, ql[ks], st[mf], 0, 0, 0);
        st[mf] = __builtin_amdgcn_mfma_f32_16x16x32_bf16(kl, qh[ks], st[mf], 0, 0, 0);
      }
    }
    __builtin_amdgcn_s_setprio(0);

    const int dtile = q0 - k0;
    float pv[4][4];
    float lmax = NEG_INF;
    if (dtile >= 192 || dtile <= -192) {
      const int C = (dtile >= 192) ? 63 : 0;
      const float cbias = (dtile >= 192) ? c2p63 : c2p0;
      #pragma unroll
      for (int mf = 0; mf < 4; mf++) {
        #pragma unroll
        for (int rr = 0; rr < 4; rr++) {
          int kj = mf * 16 + g * 4 + rr;
          float v = st[mf][rr] * inv_s + (cbias + bf2f(sp2c[kj][C]));
          v = smask[kj] ? NEG_INF : v;
          pv[mf][rr] = v;
          lmax = fmaxf(lmax, v);
        }
      }
    } else {
      const int dq = q0 + qloc - k0 + 1023;
      const ushort_t* c2prow = &sc2p[qloc][0];
      #pragma unroll
      for (int mf = 0; mf < 4; mf++) {
        #pragma unroll
        for (int rr = 0; rr < 4; rr++) {
          int kj = mf * 16 + g * 4 + rr;
          int tbi = stab[dq - kj];
          float v = st[mf][rr] * inv_s + (bf2f(c2prow[tbi]) + bf2f(sp2c[kj][tbi]));
          v = smask[kj] ? NEG_INF : v;
          pv[mf][rr] = v;
          lmax = fmaxf(lmax, v);
        }
      }
    }
    lmax = fmaxf(lmax, __shfl_xor(lmax, 16));
    lmax = fmaxf(lmax, __shfl_xor(lmax, 32));
    if (!__all(lmax <= m_run)) {
      float mnew = fmaxf(m_run, lmax);
      float fac = __expf(m_run - mnew);
      m_run = mnew;
      l_run *= fac;
      float facr[4];
      #pragma unroll
      for (int rr = 0; rr < 4; rr++) facr[rr] = __shfl(fac, g * 4 + rr);
      #pragma unroll
      for (int nf = 0; nf < 4; nf++)
        #pragma unroll
        for (int rr = 0; rr < 4; rr++) acc[nf][rr] *= facr[rr];
    }
    float psum = 0.f;
    #pragma unroll
    for (int mf = 0; mf < 4; mf++)
      #pragma unroll
      for (int rr = 0; rr < 4; rr++) {
        float e = __expf(pv[mf][rr] - m_run);
        pv[mf][rr] = e;
        psum += e;
      }
    psum += __shfl_xor(psum, 16);
    psum += __shfl_xor(psum, 32);
    l_run += psum;

    bf16x8 pa[2];
    #pragma unroll
    for (int ks = 0; ks < 2; ks++) {
      bf16x8 t;
      #pragma unroll
      for (int j = 0; j < 8; j++) {
        int src = ((2 * (g & 1) + (j >> 2)) << 4) | fr;
        float v0 = __shfl(pv[2 * ks][j & 3], src);
        float v1 = __shfl(pv[2 * ks + 1][j & 3], src);
        float pvv = (g >> 1) ? v1 : v0;
        t[j] = (short)bf16rn(pvv);
      }
      pa[ks] = t;
    }

    __builtin_amdgcn_s_setprio(1);
    #pragma unroll
    for (int nf = 0; nf < 4; nf++) {
      #pragma unroll
      for (int ks = 0; ks < 2; ks++) {
        bf16x8 vh = *(const bf16x8*)&sVh[(nf * 8 + ks * 4 + g) * 128 + fr * 8];
        bf16x8 vl = *(const bf16x8*)&sVl[(nf * 8 + ks * 4 + g) * 128 + fr * 8];
        acc[nf] = __builtin_amdgcn_mfma_f32_16x16x32_bf16(pa[ks], vh, acc[nf], 0, 0, 0);
        acc[nf] = __builtin_amdgcn_mfma_f32_16x16x32_bf16(pa[ks], vl, acc[nf], 0, 0, 0);
      }
    }
    __builtin_amdgcn_s_setprio(0);
  }

  // --- epilogue: write RAW partial acc (hi/lo) + per-row (m,l); no normalization
  ushort_t* OH = kvh ? P1H : P0H;
  ushort_t* OL = kvh ? P1L : P0L;
  if (g == 0) {
    int mi = ((kvh * 2 + b) * 16 + h) * 1024 + (q0 + qloc);
    pml[mi] = m_run;                    // m region: [0, 65536)
    pml[65536 + mi] = l_run;            // l region
  }
  #pragma unroll
  for (int nf = 0; nf < 4; nf++) {
    #pragma unroll
    for (int rr = 0; rr < 4; rr++) {
      int qrow = q0 + wid * 16 + g * 4 + rr;
      int dcol = h * HD + nf * 16 + fr;
      size_t idx = ((size_t)b * TQ + qrow) * D + dcol;
      unsigned short hh, ll;
      split2(acc[nf][rr], hh, ll);
      OH[idx] = hh;
      OL[idx] = ll;
    }
  }
}

// ---------------- split-KV merge: ctx = (p0*aA + p1*aB) / (lA*aA + lB*aB) ----------------
__global__ __launch_bounds__(256) void attn_merge(
    const ushort_t* __restrict__ P0H, const ushort_t* __restrict__ P0L,
    ushort_t* __restrict__ P1H, ushort_t* __restrict__ P1L,   // in: half1, out: final ctx
    const float* __restrict__ pml) {
  size_t i = ((size_t)blockIdx.x * 256 + threadIdx.x) * 8;
  int rowid = (int)(i >> 10);                  // b*1024 + qrow
  int b = rowid >> 10, qrow = rowid & 1023;
  int h = (int)((i & 1023) >> 6);
  int mi0 = ((0 * 2 + b) * 16 + h) * 1024 + qrow;
  int mi1 = ((1 * 2 + b) * 16 + h) * 1024 + qrow;
  float mA = pml[mi0], lA = pml[65536 + mi0];
  float mB = pml[mi1], lB = pml[65536 + mi1];
  float mm = fmaxf(mA, mB);
  float aA = __expf(mA - mm), aB = __expf(mB - mm);
  float dinv = 1.0f / (lA * aA + lB * aB);
  bf16x8 h0 = *(const bf16x8*)&P0H[i];
  bf16x8 l0 = *(const bf16x8*)&P0L[i];
  bf16x8 h1 = *(const bf16x8*)&P1H[i];
  bf16x8 l1 = *(const bf16x8*)&P1L[i];
  bf16x8 oh, ol;
  #pragma unroll
  for (int j = 0; j < 8; j++) {
    float p0 = bf2f((ushort_t)h0[j]) + bf2f((ushort_t)l0[j]);
    float p1 = bf2f((ushort_t)h1[j]) + bf2f((ushort_t)l1[j]);
    float o = (p0 * aA + p1 * aB) * dinv;
    unsigned short hh, ll;
    split2(o, hh, ll);
    oh[j] = (short)hh; ol[j] = (short)ll;
  }
  *(bf16x8*)&P1H[i] = oh;
  *(bf16x8*)&P1L[i] = ol;
}

extern "C" void kernel_launch(void* const* d_in, const int* in_sizes, int n_in,
                              void* d_out, int out_size, void* d_ws, size_t ws_size,
                              hipStream_t stream) {
  const float* query = (const float*)d_in[0];
  const float* kv    = (const float*)d_in[1];
  const float* Wq  = (const float*)d_in[2];   const float* bq  = (const float*)d_in[3];
  const float* Wk  = (const float*)d_in[4];   const float* bk  = (const float*)d_in[5];
  const float* Wv  = (const float*)d_in[6];   const float* bv  = (const float*)d_in[7];
  const float* Wo  = (const float*)d_in[8];   const float* bo  = (const float*)d_in[9];
  const float* Wpk = (const float*)d_in[10];  const float* bpk = (const float*)d_in[11];
  const float* Wpq = (const float*)d_in[12];  const float* bpq = (const float*)d_in[13];
  const float* rel_emb = (const float*)d_in[14];
  const float* ln_g = (const float*)d_in[15];
  const float* ln_b = (const float*)d_in[16];
  const unsigned char* amask = (const unsigned char*)d_in[17];

  float* ws = (float*)d_ws;
  float* rebuf   = ws + RE_OFF;
  float* poskbuf = ws + POSK_OFF;
  float* posqbuf = ws + POSQ_OFF;
  ushort_t* sbase = (ushort_t*)((char*)d_ws + SHORT_BASE_BYTES);
  ushort_t* c2pbuf = sbase + C2P_S;
  ushort_t* p2cbuf = sbase + P2C_S;
  ushort_t* QH   = sbase + QH_S;
  ushort_t* QL   = sbase + QL_S;
  ushort_t* KH   = sbase + KH_S;
  ushort_t* KL   = sbase + KL_S;
  ushort_t* VTH  = sbase + VTH_S;
  ushort_t* VTL  = sbase + VTL_S;
  ushort_t* CTXH = sbase + CTXH_S;
  ushort_t* CTXL = sbase + CTXL_S;
  ushort_t* AKVH = sbase + AKVH_S;
  ushort_t* AKVL = sbase + AKVL_S;
  unsigned char* tab = (unsigned char*)d_ws + TAB_OFF_BYTES;
  float* pml = (float*)((char*)d_ws + PML_OFF_BYTES);

  // 1. LayerNorm of rel_emb + bucket table + pre-split kv
  ln_kernel<<<64, 256, 0, stream>>>(rel_emb, ln_g, ln_b, rebuf);
  tab_kernel<<<8, 256, 0, stream>>>(tab);
  presplit_kernel<<<1024, 256, 0, stream>>>(kv, AKVH, AKVL);
  // 2. positional projections (MFMA split-bf16)
  gemm_pos<<<dim3(16, 1, 2), 256, 0, stream>>>(rebuf, Wpk, bpk, poskbuf, Wpq, bpq, posqbuf);
  // 3. Q/K/V projections fused (XCD-swizzled)
  gemm_split<<<dim3(16, 16, 3), 256, 0, stream>>>(
      query, AKVH, AKVL,  Wq, Wk, Wv,  bq, bk, bv,
      QH, QL, KH, KL, VTH, VTL, 1024);
  // 4. c2p / p2c (z-fused, bf16 out, pre-scaled by 1/sqrt(128))
  relproj_kernel<<<dim3(16, 32, 2), 256, 0, stream>>>(
      QH, QL, poskbuf, c2pbuf, KH, KL, posqbuf, p2cbuf);
  // 5. MFMA flash attention, split-KV x2 (1024 blocks, 3/CU; partial half0 -> AKV buffers)
  attn_mfma<<<1024, 256, 0, stream>>>(QH, QL, KH, KL, VTH, VTL,
                                      c2pbuf, p2cbuf, amask, tab,
                                      AKVH, AKVL, CTXH, CTXL, pml);
  // 5b. deterministic merge -> CTXH/CTXL
  attn_merge<<<1024, 256, 0, stream>>>(AKVH, AKVL, CTXH, CTXL, pml);
  // 6. output projection -> d_out
  gemm_out<<<dim3(16, 32), 256, 0, stream>>>(CTXH, CTXL, Wo, bo, (float*)d_out);
}

// Round 12
// 189.849 us; speedup vs baseline: 1.1136x; 1.1136x over previous
//
#include <hip/hip_runtime.h>
#include <hip/hip_bf16.h>
#include <math.h>

#define B   2
#define TQ  1024
#define TKV 1024
#define D   1024
#define H   16
#define HD  64
#define P   64     // 2*SPAN
#define SPAN 32

#define NEG_INF (-3.0e38f)

typedef __attribute__((ext_vector_type(8))) short bf16x8;
typedef __attribute__((ext_vector_type(4))) float f32x4;
typedef unsigned short ushort_t;

// ---------------- workspace layout ----------------
static constexpr size_t RE_OFF   = 0;                          // 64K floats
static constexpr size_t POSK_OFF = (size_t)64 * 1024;
static constexpr size_t POSQ_OFF = (size_t)128 * 1024;
static constexpr size_t FLOATS_END = (size_t)192 * 1024;
static constexpr size_t SHORT_BASE_BYTES = FLOATS_END * 4;     // 768 KB
static constexpr size_t C2P_S  = 0;
static constexpr size_t P2C_S  = (size_t)2 * 1024 * 1024;
static constexpr size_t QH_S   = (size_t)4 * 1024 * 1024;
static constexpr size_t QL_S   = (size_t)6 * 1024 * 1024;
static constexpr size_t KH_S   = (size_t)8 * 1024 * 1024;
static constexpr size_t KL_S   = (size_t)10 * 1024 * 1024;
static constexpr size_t VTH_S  = (size_t)12 * 1024 * 1024;
static constexpr size_t VTL_S  = (size_t)14 * 1024 * 1024;
static constexpr size_t CTXH_S = (size_t)16 * 1024 * 1024;
static constexpr size_t CTXL_S = (size_t)18 * 1024 * 1024;
static constexpr size_t AKVH_S = (size_t)20 * 1024 * 1024;     // pre-split kv input
static constexpr size_t AKVL_S = (size_t)22 * 1024 * 1024;
static constexpr size_t TAB_OFF_BYTES = SHORT_BASE_BYTES + (size_t)24 * 1024 * 1024 * 2;

// split x into hi (bit-truncated bf16) + lo (RN bf16 of exact residual)
__device__ __forceinline__ void split2(float x, unsigned short& h, unsigned short& l) {
  unsigned int u = __float_as_uint(x);
  h = (unsigned short)(u >> 16);
  float r = x - __uint_as_float(u & 0xffff0000u);   // exact
  unsigned int v = __float_as_uint(r);
  v += 0x7fffu + ((v >> 16) & 1u);                  // RN-even
  l = (unsigned short)(v >> 16);
}

__device__ __forceinline__ unsigned short bf16rn(float x) {
  unsigned int v = __float_as_uint(x);
  v += 0x7fffu + ((v >> 16) & 1u);
  return (unsigned short)(v >> 16);
}

__device__ __forceinline__ float bf2f(unsigned short u) {
  return __uint_as_float(((unsigned int)u) << 16);
}

// ---------------- fused front: presplit(kv) + layernorm(rel_emb) + bucket table ----------------
__global__ __launch_bounds__(256) void fused_pre(const float* __restrict__ kv,
    ushort_t* __restrict__ oh, ushort_t* __restrict__ ol,
    const float* __restrict__ re_in, const float* __restrict__ ln_g,
    const float* __restrict__ ln_b, float* __restrict__ re_out,
    unsigned char* __restrict__ tab) {
  const int bid = blockIdx.x;
  const int tid = threadIdx.x;
  if (bid < 1024) {
    // presplit kv
    size_t i = ((size_t)bid * 256 + tid) * 8;
    float4 a = *(const float4*)&kv[i];
    float4 b = *(const float4*)&kv[i + 4];
    float xs[8] = {a.x, a.y, a.z, a.w, b.x, b.y, b.z, b.w};
    bf16x8 th, tl;
    #pragma unroll
    for (int j = 0; j < 8; j++) {
      unsigned short hh, ll;
      split2(xs[j], hh, ll);
      th[j] = (short)hh; tl[j] = (short)ll;
    }
    *(bf16x8*)&oh[i] = th;
    *(bf16x8*)&ol[i] = tl;
  } else if (bid < 1088) {
    // layernorm row
    const int row = bid - 1024;
    const float* xr = re_in + (size_t)row * D;
    __shared__ float red[4];
    float s = 0.f;
    for (int i = tid; i < D; i += 256) s += xr[i];
    #pragma unroll
    for (int off = 32; off; off >>= 1) s += __shfl_down(s, off);
    if ((tid & 63) == 0) red[tid >> 6] = s;
    __syncthreads();
    float mu = (red[0] + red[1] + red[2] + red[3]) * (1.0f / D);
    __syncthreads();
    float vs = 0.f;
    for (int i = tid; i < D; i += 256) { float dd = xr[i] - mu; vs += dd * dd; }
    #pragma unroll
    for (int off = 32; off; off >>= 1) vs += __shfl_down(vs, off);
    if ((tid & 63) == 0) red[tid >> 6] = vs;
    __syncthreads();
    float var = (red[0] + red[1] + red[2] + red[3]) * (1.0f / D);
    float rs = rsqrtf(var + 1e-5f);
    for (int i = tid; i < D; i += 256)
      re_out[(size_t)row * D + i] = (xr[i] - mu) * rs * ln_g[i] + ln_b[i];
  } else {
    // bucket table
    int i = (bid - 1088) * 256 + tid;
    if (i >= 2047) return;
    int d = i - 1023;
    int ad = d < 0 ? -d : d;
    int bucket;
    if (ad <= 16) {
      bucket = d;
    } else {
      double x = log((double)ad / 16.0) / log(127.0 / 16.0) * 15.0;
      double xr = floor(x + 0.5);
      double xc = (fabs(x - xr) < 1e-9) ? xr : ceil(x);
      int li = (int)xc + 16;
      bucket = (d > 0) ? li : -li;
    }
    int t = bucket + SPAN;
    t = t < 0 ? 0 : (t > 63 ? 63 : t);
    tab[i] = (unsigned char)t;
  }
}

// ---------------- MFMA split-bf16 pos projections: C[64,1024] = re @ W^T + b ----------------
__global__ __launch_bounds__(256) void gemm_pos(const float* __restrict__ A,
    const float* __restrict__ W0, const float* __restrict__ b0, float* __restrict__ C0,
    const float* __restrict__ W1, const float* __restrict__ b1, float* __restrict__ C1) {
  const float* W = blockIdx.z ? W1 : W0;
  const float* bias = blockIdx.z ? b1 : b0;
  float* C = blockIdx.z ? C1 : C0;

  __shared__ short sAh[64 * 32], sAl[64 * 32], sBh[64 * 32], sBl[64 * 32];
  const int t = threadIdx.x;
  const int bn = blockIdx.x * 64;
  const int wid = t >> 6, lane = t & 63;
  const int wr = wid >> 1, wc = wid & 1;
  const int fr = lane & 15, fo = (lane >> 4) * 8;
  const int srow = t >> 3, scol = (t & 7) * 4;

  f32x4 acc[2][2];
  #pragma unroll
  for (int i = 0; i < 2; i++)
    #pragma unroll
    for (int j = 0; j < 2; j++) acc[i][j] = (f32x4){0.f, 0.f, 0.f, 0.f};

  float4 rA[2], rW[2];
  auto ld = [&](int k0) {
    #pragma unroll
    for (int i = 0; i < 2; i++) {
      rA[i] = *(const float4*)&A[(size_t)(srow + 32 * i) * 1024 + k0 + scol];
      rW[i] = *(const float4*)&W[(size_t)(bn + srow + 32 * i) * 1024 + k0 + scol];
    }
  };
  ld(0);

  for (int k0 = 0; k0 < 1024; k0 += 32) {
    __syncthreads();
    #pragma unroll
    for (int i = 0; i < 2; i++) {
      int row = srow + 32 * i;
      unsigned short h0,h1,h2,h3,l0,l1,l2,l3;
      split2(rA[i].x,h0,l0); split2(rA[i].y,h1,l1); split2(rA[i].z,h2,l2); split2(rA[i].w,h3,l3);
      *(short4*)&sAh[row * 32 + scol] = make_short4((short)h0,(short)h1,(short)h2,(short)h3);
      *(short4*)&sAl[row * 32 + scol] = make_short4((short)l0,(short)l1,(short)l2,(short)l3);
      split2(rW[i].x,h0,l0); split2(rW[i].y,h1,l1); split2(rW[i].z,h2,l2); split2(rW[i].w,h3,l3);
      *(short4*)&sBh[row * 32 + scol] = make_short4((short)h0,(short)h1,(short)h2,(short)h3);
      *(short4*)&sBl[row * 32 + scol] = make_short4((short)l0,(short)l1,(short)l2,(short)l3);
    }
    if (k0 + 32 < 1024) ld(k0 + 32);
    __syncthreads();

    bf16x8 ah[2], al[2], bh[2], bl[2];
    #pragma unroll
    for (int mf = 0; mf < 2; mf++) {
      int r = (wr * 32 + mf * 16 + fr) * 32 + fo;
      ah[mf] = *(const bf16x8*)&sAh[r];
      al[mf] = *(const bf16x8*)&sAl[r];
    }
    #pragma unroll
    for (int nf = 0; nf < 2; nf++) {
      int r = (wc * 32 + nf * 16 + fr) * 32 + fo;
      bh[nf] = *(const bf16x8*)&sBh[r];
      bl[nf] = *(const bf16x8*)&sBl[r];
    }
    #pragma unroll
    for (int mf = 0; mf < 2; mf++)
      #pragma unroll
      for (int nf = 0; nf < 2; nf++) {
        acc[mf][nf] = __builtin_amdgcn_mfma_f32_16x16x32_bf16(ah[mf], bh[nf], acc[mf][nf], 0, 0, 0);
        acc[mf][nf] = __builtin_amdgcn_mfma_f32_16x16x32_bf16(ah[mf], bl[nf], acc[mf][nf], 0, 0, 0);
        acc[mf][nf] = __builtin_amdgcn_mfma_f32_16x16x32_bf16(al[mf], bh[nf], acc[mf][nf], 0, 0, 0);
      }
  }

  #pragma unroll
  for (int mf = 0; mf < 2; mf++) {
    int rbase = wr * 32 + mf * 16 + (lane >> 4) * 4;
    #pragma unroll
    for (int nf = 0; nf < 2; nf++) {
      int col = bn + wc * 32 + nf * 16 + fr;
      float bb = bias[col];
      #pragma unroll
      for (int r = 0; r < 4; r++)
        C[(size_t)(rbase + r) * 1024 + col] = acc[mf][nf][r] + bb;
    }
  }
}

// ---------------- split-bf16 MFMA GEMM (QKV): BM=128, BN=64, BK=32 ----------------
// Per-XCD 4bm x 8bn tiling: working set ~2MB A + 2MB W fits one XCD's L2.
__global__ __launch_bounds__(256) void gemm_split(
    const float* __restrict__ Aq,
    const ushort_t* __restrict__ AKVH, const ushort_t* __restrict__ AKVL,
    const float* __restrict__ W0, const float* __restrict__ W1, const float* __restrict__ W2,
    const float* __restrict__ b0, const float* __restrict__ b1, const float* __restrict__ b2,
    ushort_t* __restrict__ QH_, ushort_t* __restrict__ QL_,
    ushort_t* __restrict__ KH_, ushort_t* __restrict__ KL_,
    ushort_t* __restrict__ VH_, ushort_t* __restrict__ VL_,
    int K) {
  const int z = blockIdx.z;
  const float* W = (z == 0) ? W0 : (z == 1) ? W1 : W2;
  const float* bias = (z == 0) ? b0 : (z == 1) ? b1 : b2;

  // L2-aware swizzle: XCD x owns 4 bm-panels x 8 bn-panels
  const int flat2 = blockIdx.y * 16 + blockIdx.x;
  const int x = flat2 & 7, w = flat2 >> 3;          // w in [0,32)
  const int bm = ((x >> 1) * 4 + (w >> 3)) * 128;
  const int bn = ((x & 1) * 8 + (w & 7)) * 64;

  __shared__ short sAhi[128 * 32];
  __shared__ short sAlo[128 * 32];
  __shared__ short sBhi[64 * 32];
  __shared__ short sBlo[64 * 32];

  const int t = threadIdx.x;
  const int wid = t >> 6, lane = t & 63;
  const int wr = wid >> 1, wc = wid & 1;
  const int fr = lane & 15, fo = (lane >> 4) * 8;

  f32x4 acc[4][2];
  #pragma unroll
  for (int i = 0; i < 4; i++)
    #pragma unroll
    for (int j = 0; j < 2; j++)
      acc[i][j] = (f32x4){0.f, 0.f, 0.f, 0.f};

  const int srow = t >> 3;
  const int scol = (t & 7) * 4;
  const int ar = t >> 1;
  const int ac = (t & 1) * 16;

  float4 rA[4], rW[2];
  bf16x8 rAH[2], rAL[2];
  auto ld = [&](int k0) {
    if (z == 0) {
      #pragma unroll
      for (int i = 0; i < 4; i++)
        rA[i] = *(const float4*)&Aq[(size_t)(bm + srow + 32 * i) * K + k0 + scol];
    } else {
      const size_t abase = (size_t)(bm + ar) * K + k0 + ac;
      rAH[0] = *(const bf16x8*)&AKVH[abase];
      rAH[1] = *(const bf16x8*)&AKVH[abase + 8];
      rAL[0] = *(const bf16x8*)&AKVL[abase];
      rAL[1] = *(const bf16x8*)&AKVL[abase + 8];
    }
    #pragma unroll
    for (int i = 0; i < 2; i++)
      rW[i] = *(const float4*)&W[(size_t)(bn + srow + 32 * i) * K + k0 + scol];
  };
  ld(0);

  for (int k0 = 0; k0 < K; k0 += 32) {
    __syncthreads();
    if (z == 0) {
      #pragma unroll
      for (int i = 0; i < 4; i++) {
        int row = srow + 32 * i;
        unsigned short h0, h1, h2, h3, l0, l1, l2, l3;
        split2(rA[i].x, h0, l0); split2(rA[i].y, h1, l1); split2(rA[i].z, h2, l2); split2(rA[i].w, h3, l3);
        *(short4*)&sAhi[row * 32 + scol] = make_short4((short)h0, (short)h1, (short)h2, (short)h3);
        *(short4*)&sAlo[row * 32 + scol] = make_short4((short)l0, (short)l1, (short)l2, (short)l3);
      }
    } else {
      *(bf16x8*)&sAhi[ar * 32 + ac]     = rAH[0];
      *(bf16x8*)&sAhi[ar * 32 + ac + 8] = rAH[1];
      *(bf16x8*)&sAlo[ar * 32 + ac]     = rAL[0];
      *(bf16x8*)&sAlo[ar * 32 + ac + 8] = rAL[1];
    }
    #pragma unroll
    for (int i = 0; i < 2; i++) {
      int row = srow + 32 * i;
      unsigned short h0, h1, h2, h3, l0, l1, l2, l3;
      split2(rW[i].x, h0, l0); split2(rW[i].y, h1, l1); split2(rW[i].z, h2, l2); split2(rW[i].w, h3, l3);
      *(short4*)&sBhi[row * 32 + scol] = make_short4((short)h0, (short)h1, (short)h2, (short)h3);
      *(short4*)&sBlo[row * 32 + scol] = make_short4((short)l0, (short)l1, (short)l2, (short)l3);
    }
    if (k0 + 32 < K) ld(k0 + 32);
    __syncthreads();

    bf16x8 ah[4], al[4], bh[2], bl[2];
    #pragma unroll
    for (int mf = 0; mf < 4; mf++) {
      int r = (wr * 64 + mf * 16 + fr) * 32 + fo;
      ah[mf] = *(const bf16x8*)&sAhi[r];
      al[mf] = *(const bf16x8*)&sAlo[r];
    }
    #pragma unroll
    for (int nf = 0; nf < 2; nf++) {
      int r = (wc * 32 + nf * 16 + fr) * 32 + fo;
      bh[nf] = *(const bf16x8*)&sBhi[r];
      bl[nf] = *(const bf16x8*)&sBlo[r];
    }
    #pragma unroll
    for (int mf = 0; mf < 4; mf++)
      #pragma unroll
      for (int nf = 0; nf < 2; nf++) {
        acc[mf][nf] = __builtin_amdgcn_mfma_f32_16x16x32_bf16(ah[mf], bh[nf], acc[mf][nf], 0, 0, 0);
        acc[mf][nf] = __builtin_amdgcn_mfma_f32_16x16x32_bf16(ah[mf], bl[nf], acc[mf][nf], 0, 0, 0);
        acc[mf][nf] = __builtin_amdgcn_mfma_f32_16x16x32_bf16(al[mf], bh[nf], acc[mf][nf], 0, 0, 0);
      }
  }

  if (z == 2) {
    #pragma unroll
    for (int mf = 0; mf < 4; mf++) {
      int m0 = bm + wr * 64 + mf * 16 + (lane >> 4) * 4;
      int bb2 = m0 >> 10, t0 = m0 & 1023;
      #pragma unroll
      for (int nf = 0; nf < 2; nf++) {
        int col = bn + wc * 32 + nf * 16 + fr;
        int hh = col >> 6, dd = col & 63;
        float bvv = bias[col];
        unsigned short h4[4], l4[4];
        #pragma unroll
        for (int r = 0; r < 4; r++) split2(acc[mf][nf][r] + bvv, h4[r], l4[r]);
        size_t dst = (((size_t)bb2 * 16 + hh) * 64 + dd) * 1024 + t0;
        *(short4*)&VH_[dst] = make_short4((short)h4[0], (short)h4[1], (short)h4[2], (short)h4[3]);
        *(short4*)&VL_[dst] = make_short4((short)l4[0], (short)l4[1], (short)l4[2], (short)l4[3]);
      }
    }
  } else {
    ushort_t* OH = (z == 0) ? QH_ : KH_;
    ushort_t* OL = (z == 0) ? QL_ : KL_;
    #pragma unroll
    for (int mf = 0; mf < 4; mf++) {
      int rbase = bm + wr * 64 + mf * 16 + (lane >> 4) * 4;
      #pragma unroll
      for (int nf = 0; nf < 2; nf++) {
        int col = bn + wc * 32 + nf * 16 + fr;
        float bb = bias[col];
        #pragma unroll
        for (int r = 0; r < 4; r++) {
          unsigned short hh, ll;
          split2(acc[mf][nf][r] + bb, hh, ll);
          OH[(size_t)(rbase + r) * 1024 + col] = hh;
          OL[(size_t)(rbase + r) * 1024 + col] = ll;
        }
      }
    }
  }
}

// ---------------- out projection: C[2048,1024] = ctx(hi/lo bf16) @ Wo^T + bo ----------------
__global__ __launch_bounds__(256) void gemm_out(
    const ushort_t* __restrict__ AH, const ushort_t* __restrict__ AL,
    const float* __restrict__ W, const float* __restrict__ bias, float* __restrict__ C) {
  __shared__ short sAh[64 * 32], sAl[64 * 32], sBh[64 * 32], sBl[64 * 32];
  const int t = threadIdx.x;
  // L2-aware swizzle: XCD x owns 8 bm-panels x 8 bn-panels
  const int flat2 = blockIdx.y * 16 + blockIdx.x;
  const int x = flat2 & 7, w = flat2 >> 3;          // w in [0,64)
  const int bm = ((x >> 1) * 8 + (w >> 3)) * 64;
  const int bn = ((x & 1) * 8 + (w & 7)) * 64;
  const int wid = t >> 6, lane = t & 63;
  const int wr = wid >> 1, wc = wid & 1;
  const int fr = lane & 15, fo = (lane >> 4) * 8;
  const int arow = t >> 2, achk = (t & 3) * 8;
  const int srow = t >> 3, scol = (t & 7) * 4;

  f32x4 acc[2][2];
  #pragma unroll
  for (int i = 0; i < 2; i++)
    #pragma unroll
    for (int j = 0; j < 2; j++) acc[i][j] = (f32x4){0.f, 0.f, 0.f, 0.f};

  bf16x8 rAH, rAL;
  float4 rW[2];
  auto ld = [&](int k0) {
    rAH = *(const bf16x8*)&AH[(size_t)(bm + arow) * 1024 + k0 + achk];
    rAL = *(const bf16x8*)&AL[(size_t)(bm + arow) * 1024 + k0 + achk];
    #pragma unroll
    for (int i = 0; i < 2; i++)
      rW[i] = *(const float4*)&W[(size_t)(bn + srow + 32 * i) * 1024 + k0 + scol];
  };
  ld(0);

  for (int k0 = 0; k0 < 1024; k0 += 32) {
    __syncthreads();
    *(bf16x8*)&sAh[arow * 32 + achk] = rAH;
    *(bf16x8*)&sAl[arow * 32 + achk] = rAL;
    #pragma unroll
    for (int i = 0; i < 2; i++) {
      int row = srow + 32 * i;
      unsigned short h0,h1,h2,h3,l0,l1,l2,l3;
      split2(rW[i].x,h0,l0); split2(rW[i].y,h1,l1); split2(rW[i].z,h2,l2); split2(rW[i].w,h3,l3);
      *(short4*)&sBh[row * 32 + scol] = make_short4((short)h0,(short)h1,(short)h2,(short)h3);
      *(short4*)&sBl[row * 32 + scol] = make_short4((short)l0,(short)l1,(short)l2,(short)l3);
    }
    if (k0 + 32 < 1024) ld(k0 + 32);
    __syncthreads();

    bf16x8 ah[2], al[2], bh[2], bl[2];
    #pragma unroll
    for (int mf = 0; mf < 2; mf++) {
      int r = (wr * 32 + mf * 16 + fr) * 32 + fo;
      ah[mf] = *(const bf16x8*)&sAh[r];
      al[mf] = *(const bf16x8*)&sAl[r];
    }
    #pragma unroll
    for (int nf = 0; nf < 2; nf++) {
      int r = (wc * 32 + nf * 16 + fr) * 32 + fo;
      bh[nf] = *(const bf16x8*)&sBh[r];
      bl[nf] = *(const bf16x8*)&sBl[r];
    }
    #pragma unroll
    for (int mf = 0; mf < 2; mf++)
      #pragma unroll
      for (int nf = 0; nf < 2; nf++) {
        acc[mf][nf] = __builtin_amdgcn_mfma_f32_16x16x32_bf16(ah[mf], bh[nf], acc[mf][nf], 0, 0, 0);
        acc[mf][nf] = __builtin_amdgcn_mfma_f32_16x16x32_bf16(ah[mf], bl[nf], acc[mf][nf], 0, 0, 0);
        acc[mf][nf] = __builtin_amdgcn_mfma_f32_16x16x32_bf16(al[mf], bh[nf], acc[mf][nf], 0, 0, 0);
      }
  }

  #pragma unroll
  for (int mf = 0; mf < 2; mf++) {
    int rbase = bm + wr * 32 + mf * 16 + (lane >> 4) * 4;
    #pragma unroll
    for (int nf = 0; nf < 2; nf++) {
      int col = bn + wc * 32 + nf * 16 + fr;
      float bb = bias[col];
      #pragma unroll
      for (int r = 0; r < 4; r++)
        C[(size_t)(rbase + r) * 1024 + col] = acc[mf][nf][r] + bb;
    }
  }
}

// ---------------- MFMA rel projection: out[bh][t][p] = sum_d X[b,t,h*64+d] * POS[p][h*64+d] ----
// grid (4, 32, 2): block = (bh, 256 t-rows); 4 waves x 64 rows; pos tile staged split-bf16 in LDS.
// Output bf16, pre-scaled by 1/sqrt(128). z0: X=Q -> c2p; z1: X=K -> p2c.
__global__ __launch_bounds__(256) void relproj_mfma(
    const ushort_t* __restrict__ QH, const ushort_t* __restrict__ QL,
    const ushort_t* __restrict__ KH, const ushort_t* __restrict__ KL,
    const float* __restrict__ POSK, const float* __restrict__ POSQ,
    ushort_t* __restrict__ O0, ushort_t* __restrict__ O1) {
  const int z = blockIdx.z;
  const ushort_t* XH = z ? KH : QH;
  const ushort_t* XL = z ? KL : QL;
  const float* POS = z ? POSQ : POSK;
  ushort_t* out = z ? O1 : O0;
  const int bh = blockIdx.y, b = bh >> 4, h = bh & 15;
  const int t0 = blockIdx.x * 256;

  const int tid = threadIdx.x;
  const int wid = tid >> 6, lane = tid & 63;
  const int g = lane >> 4, fr = lane & 15;

  // B-fragment subtiled layout: sub = nf*8 + ks*4 + g, slot fr (8 shorts)
  __shared__ __align__(16) short sPh[4096], sPl[4096];
  {
    const int sr = tid >> 2;              // p row 0..63
    const int cb = (tid & 3) * 16;        // d chunk
    const float* pp = &POS[(size_t)sr * 1024 + h * HD + cb];
    #pragma unroll
    for (int o = 0; o < 16; o += 8) {
      float4 a = *(const float4*)(pp + o);
      float4 c = *(const float4*)(pp + o + 4);
      float xs[8] = {a.x, a.y, a.z, a.w, c.x, c.y, c.z, c.w};
      bf16x8 th, tl;
      #pragma unroll
      for (int j = 0; j < 8; j++) {
        unsigned short hh, ll;
        split2(xs[j], hh, ll);
        th[j] = (short)hh; tl[j] = (short)ll;
      }
      int d0 = cb + o;
      int addr = (((sr >> 4) * 8) + ((d0 >> 5) * 4) + ((d0 >> 3) & 3)) * 128 + (sr & 15) * 8;
      *(bf16x8*)&sPh[addr] = th;
      *(bf16x8*)&sPl[addr] = tl;
    }
  }
  __syncthreads();

  const float inv_ps = 0.08838834764831845f;  // 1/sqrt(128)
  f32x4 acc[4][4];
  #pragma unroll
  for (int mf = 0; mf < 4; mf++)
    #pragma unroll
    for (int nf = 0; nf < 4; nf++) acc[mf][nf] = (f32x4){0.f, 0.f, 0.f, 0.f};

  #pragma unroll
  for (int mf = 0; mf < 4; mf++) {
    const int trow = t0 + wid * 64 + mf * 16 + fr;
    const size_t xbase = ((size_t)b * TQ + trow) * D + h * HD;
    #pragma unroll
    for (int ks = 0; ks < 2; ks++) {
      bf16x8 ah = *(const bf16x8*)&XH[xbase + ks * 32 + g * 8];
      bf16x8 al = *(const bf16x8*)&XL[xbase + ks * 32 + g * 8];
      #pragma unroll
      for (int nf = 0; nf < 4; nf++) {
        bf16x8 bhf = *(const bf16x8*)&sPh[(nf * 8 + ks * 4 + g) * 128 + fr * 8];
        bf16x8 blf = *(const bf16x8*)&sPl[(nf * 8 + ks * 4 + g) * 128 + fr * 8];
        acc[mf][nf] = __builtin_amdgcn_mfma_f32_16x16x32_bf16(ah, bhf, acc[mf][nf], 0, 0, 0);
        acc[mf][nf] = __builtin_amdgcn_mfma_f32_16x16x32_bf16(ah, blf, acc[mf][nf], 0, 0, 0);
        acc[mf][nf] = __builtin_amdgcn_mfma_f32_16x16x32_bf16(al, bhf, acc[mf][nf], 0, 0, 0);
      }
    }
  }

  // store: row t = t0 + wid*64 + mf*16 + g*4 + rr, col p = nf*16 + fr
  #pragma unroll
  for (int mf = 0; mf < 4; mf++) {
    #pragma unroll
    for (int nf = 0; nf < 4; nf++) {
      int p = nf * 16 + fr;
      #pragma unroll
      for (int rr = 0; rr < 4; rr++) {
        int tt = t0 + wid * 64 + mf * 16 + g * 4 + rr;
        out[((size_t)bh * TQ + tt) * P + p] = bf16rn(acc[mf][nf][rr] * inv_ps);
      }
    }
  }
}

// ---------------- MFMA flash attention with disentangled bias (round-10 exact) ----------------
__global__ __launch_bounds__(256) void attn_mfma(
    const ushort_t* __restrict__ QHB, const ushort_t* __restrict__ QLB,
    const ushort_t* __restrict__ KH, const ushort_t* __restrict__ KL,
    const ushort_t* __restrict__ VTH, const ushort_t* __restrict__ VTL,
    const ushort_t* __restrict__ c2p, const ushort_t* __restrict__ p2c,
    const unsigned char* __restrict__ mask, const unsigned char* __restrict__ tab,
    ushort_t* __restrict__ CTXH, ushort_t* __restrict__ CTXL) {
  const int flat = blockIdx.y * gridDim.x + blockIdx.x;   // 0..511
  const int nid = (flat & 7) * 64 + (flat >> 3);          // bijective (512 % 8 == 0)
  const int bh = nid >> 4, b = bh >> 4, h = bh & 15;
  const int q0 = (nid & 15) * 64;

  const int tid = threadIdx.x;
  const int wid = tid >> 6, lane = tid & 63;
  const int g = lane >> 4, fr = lane & 15;

  __shared__ __align__(16) short sKh[4096], sKl[4096], sVh[4096], sVl[4096];
  __shared__ __align__(16) ushort_t sc2p[64][72];
  __shared__ __align__(16) ushort_t sp2c[64][72];
  __shared__ unsigned char stab[2048];
  __shared__ unsigned char smask[64];

  bf16x8 qh[2], ql[2];
  {
    const int qrow = q0 + wid * 16 + fr;
    const size_t qidx = ((size_t)b * TQ + qrow) * D + h * HD + g * 8;
    #pragma unroll
    for (int ks = 0; ks < 2; ks++) {
      qh[ks] = *(const bf16x8*)&QHB[qidx + ks * 32];
      ql[ks] = *(const bf16x8*)&QLB[qidx + ks * 32];
    }
  }

  const int sr = tid >> 2;
  const int sj0 = tid & 3;
  const int smf = sr >> 4, sfr = sr & 15;
  const int cb = (tid & 3) * 16;
  const int qloc = wid * 16 + fr;

  {
    const ushort_t* cp = c2p + ((size_t)bh * TQ + q0 + sr) * P + cb;
    *(bf16x8*)&sc2p[sr][cb]     = *(const bf16x8*)cp;
    *(bf16x8*)&sc2p[sr][cb + 8] = *(const bf16x8*)(cp + 8);
  }
  for (int i = tid; i < 2047; i += 256) stab[i] = tab[i];
  __syncthreads();
  const float c2p0  = bf2f(sc2p[qloc][0]);
  const float c2p63 = bf2f(sc2p[qloc][63]);

  f32x4 acc[4];
  #pragma unroll
  for (int nf = 0; nf < 4; nf++) acc[nf] = (f32x4){0.f, 0.f, 0.f, 0.f};
  float m_run = NEG_INF, l_run = 0.f;

  const float inv_s = 0.07216878364870323f;  // 1/sqrt(192)

  bf16x8 rKh[2], rKl[2], rVh[2], rVl[2], rP0, rP1;
  unsigned char rmask = 0;

  auto load_tile = [&](int kt) {
    const int k0n = kt * 64;
    const size_t kbase = ((size_t)b * TKV + k0n + sr) * D + h * HD;
    const size_t vbase = ((size_t)bh * HD + sr) * TKV + k0n;
    const ushort_t* pp = p2c + ((size_t)bh * TKV + k0n + sr) * P + cb;
    #pragma unroll
    for (int u = 0; u < 2; u++) {
      int jj = sj0 + u * 4;
      rKh[u] = *(const bf16x8*)(KH + kbase + jj * 8);
      rKl[u] = *(const bf16x8*)(KL + kbase + jj * 8);
      rVh[u] = *(const bf16x8*)(VTH + vbase + jj * 8);
      rVl[u] = *(const bf16x8*)(VTL + vbase + jj * 8);
    }
    rP0 = *(const bf16x8*)pp;
    rP1 = *(const bf16x8*)(pp + 8);
    if (tid < 64) rmask = mask[(size_t)b * TKV + k0n + tid];
  };

  load_tile(0);

  for (int kt = 0; kt < TKV / 64; kt++) {
    const int k0 = kt * 64;
    __syncthreads();
    #pragma unroll
    for (int u = 0; u < 2; u++) {
      int jj = sj0 + u * 4;
      int sub = smf * 8 + (jj >> 2) * 4 + (jj & 3);
      *(bf16x8*)&sKh[sub * 128 + sfr * 8] = rKh[u];
      *(bf16x8*)&sKl[sub * 128 + sfr * 8] = rKl[u];
      *(bf16x8*)&sVh[sub * 128 + sfr * 8] = rVh[u];
      *(bf16x8*)&sVl[sub * 128 + sfr * 8] = rVl[u];
    }
    *(bf16x8*)&sp2c[sr][cb]     = rP0;
    *(bf16x8*)&sp2c[sr][cb + 8] = rP1;
    if (tid < 64) smask[tid] = rmask;
    if (kt + 1 < TKV / 64) load_tile(kt + 1);
    __syncthreads();

    f32x4 st[4];
    #pragma unroll
    for (int mf = 0; mf < 4; mf++) st[mf] = (f32x4){0.f, 0.f, 0.f, 0.f};
    __builtin_amdgcn_s_setprio(1);
    #pragma unroll
    for (int mf = 0; mf < 4; mf++) {
      #pragma unroll
      for (int ks = 0; ks < 2; ks++) {
        bf16x8 kh = *(const bf16x8*)&sKh[(mf * 8 + ks * 4 + g) * 128 + fr * 8];
        bf16x8 kl = *(const bf16x8*)&sKl[(mf * 8 + ks * 4 + g) * 128 + fr * 8];
        st[mf] = __builtin_amdgcn_mfma_f32_16x16x32_bf16(kh, qh[ks], st[mf], 0, 0, 0);
        st[mf] = __builtin_amdgcn_mfma_f32_16x16x32_bf16(kh, ql[ks], st[mf], 0, 0, 0);
        st[mf] = __builtin_amdgcn_mfma_f32_16x16x32_bf16(kl, qh[ks], st[mf], 0, 0, 0);
      }
    }
    __builtin_amdgcn_s_setprio(0);

    const int dtile = q0 - k0;
    float pv[4][4];
    float lmax = NEG_INF;
    if (dtile >= 192 || dtile <= -192) {
      const int C = (dtile >= 192) ? 63 : 0;
      const float cbias = (dtile >= 192) ? c2p63 : c2p0;
      #pragma unroll
      for (int mf = 0; mf < 4; mf++) {
        #pragma unroll
        for (int rr = 0; rr < 4; rr++) {
          int kj = mf * 16 + g * 4 + rr;
          float v = st[mf][rr] * inv_s + (cbias + bf2f(sp2c[kj][C]));
          v = smask[kj] ? NEG_INF : v;
          pv[mf][rr] = v;
          lmax = fmaxf(lmax, v);
        }
      }
    } else {
      const int dq = q0 + qloc - k0 + 1023;
      const ushort_t* c2prow = &sc2p[qloc][0];
      #pragma unroll
      for (int mf = 0; mf < 4; mf++) {
        #pragma unroll
        for (int rr = 0; rr < 4; rr++) {
          int kj = mf * 16 + g * 4 + rr;
          int tbi = stab[dq - kj];
          float v = st[mf][rr] * inv_s + (bf2f(c2prow[tbi]) + bf2f(sp2c[kj][tbi]));
          v = smask[kj] ? NEG_INF : v;
          pv[mf][rr] = v;
          lmax = fmaxf(lmax, v);
        }
      }
    }
    lmax = fmaxf(lmax, __shfl_xor(lmax, 16));
    lmax = fmaxf(lmax, __shfl_xor(lmax, 32));
    if (!__all(lmax <= m_run)) {
      float mnew = fmaxf(m_run, lmax);
      float fac = __expf(m_run - mnew);
      m_run = mnew;
      l_run *= fac;
      float facr[4];
      #pragma unroll
      for (int rr = 0; rr < 4; rr++) facr[rr] = __shfl(fac, g * 4 + rr);
      #pragma unroll
      for (int nf = 0; nf < 4; nf++)
        #pragma unroll
        for (int rr = 0; rr < 4; rr++) acc[nf][rr] *= facr[rr];
    }
    float psum = 0.f;
    #pragma unroll
    for (int mf = 0; mf < 4; mf++)
      #pragma unroll
      for (int rr = 0; rr < 4; rr++) {
        float e = __expf(pv[mf][rr] - m_run);
        pv[mf][rr] = e;
        psum += e;
      }
    psum += __shfl_xor(psum, 16);
    psum += __shfl_xor(psum, 32);
    l_run += psum;

    bf16x8 pa[2];
    #pragma unroll
    for (int ks = 0; ks < 2; ks++) {
      bf16x8 t;
      #pragma unroll
      for (int j = 0; j < 8; j++) {
        int src = ((2 * (g & 1) + (j >> 2)) << 4) | fr;
        float v0 = __shfl(pv[2 * ks][j & 3], src);
        float v1 = __shfl(pv[2 * ks + 1][j & 3], src);
        float pvv = (g >> 1) ? v1 : v0;
        t[j] = (short)bf16rn(pvv);
      }
      pa[ks] = t;
    }

    __builtin_amdgcn_s_setprio(1);
    #pragma unroll
    for (int nf = 0; nf < 4; nf++) {
      #pragma unroll
      for (int ks = 0; ks < 2; ks++) {
        bf16x8 vh = *(const bf16x8*)&sVh[(nf * 8 + ks * 4 + g) * 128 + fr * 8];
        bf16x8 vl = *(const bf16x8*)&sVl[(nf * 8 + ks * 4 + g) * 128 + fr * 8];
        acc[nf] = __builtin_amdgcn_mfma_f32_16x16x32_bf16(pa[ks], vh, acc[nf], 0, 0, 0);
        acc[nf] = __builtin_amdgcn_mfma_f32_16x16x32_bf16(pa[ks], vl, acc[nf], 0, 0, 0);
      }
    }
    __builtin_amdgcn_s_setprio(0);
  }

  float invl[4];
  #pragma unroll
  for (int rr = 0; rr < 4; rr++) invl[rr] = 1.0f / __shfl(l_run, g * 4 + rr);
  #pragma unroll
  for (int nf = 0; nf < 4; nf++) {
    #pragma unroll
    for (int rr = 0; rr < 4; rr++) {
      int qrow = q0 + wid * 16 + g * 4 + rr;
      int dcol = h * HD + nf * 16 + fr;
      size_t idx = ((size_t)b * TQ + qrow) * D + dcol;
      unsigned short hh, ll;
      split2(acc[nf][rr] * invl[rr], hh, ll);
      CTXH[idx] = hh;
      CTXL[idx] = ll;
    }
  }
}

extern "C" void kernel_launch(void* const* d_in, const int* in_sizes, int n_in,
                              void* d_out, int out_size, void* d_ws, size_t ws_size,
                              hipStream_t stream) {
  const float* query = (const float*)d_in[0];
  const float* kv    = (const float*)d_in[1];
  const float* Wq  = (const float*)d_in[2];   const float* bq  = (const float*)d_in[3];
  const float* Wk  = (const float*)d_in[4];   const float* bk  = (const float*)d_in[5];
  const float* Wv  = (const float*)d_in[6];   const float* bv  = (const float*)d_in[7];
  const float* Wo  = (const float*)d_in[8];   const float* bo  = (const float*)d_in[9];
  const float* Wpk = (const float*)d_in[10];  const float* bpk = (const float*)d_in[11];
  const float* Wpq = (const float*)d_in[12];  const float* bpq = (const float*)d_in[13];
  const float* rel_emb = (const float*)d_in[14];
  const float* ln_g = (const float*)d_in[15];
  const float* ln_b = (const float*)d_in[16];
  const unsigned char* amask = (const unsigned char*)d_in[17];

  float* ws = (float*)d_ws;
  float* rebuf   = ws + RE_OFF;
  float* poskbuf = ws + POSK_OFF;
  float* posqbuf = ws + POSQ_OFF;
  ushort_t* sbase = (ushort_t*)((char*)d_ws + SHORT_BASE_BYTES);
  ushort_t* c2pbuf = sbase + C2P_S;
  ushort_t* p2cbuf = sbase + P2C_S;
  ushort_t* QH   = sbase + QH_S;
  ushort_t* QL   = sbase + QL_S;
  ushort_t* KH   = sbase + KH_S;
  ushort_t* KL   = sbase + KL_S;
  ushort_t* VTH  = sbase + VTH_S;
  ushort_t* VTL  = sbase + VTL_S;
  ushort_t* CTXH = sbase + CTXH_S;
  ushort_t* CTXL = sbase + CTXL_S;
  ushort_t* AKVH = sbase + AKVH_S;
  ushort_t* AKVL = sbase + AKVL_S;
  unsigned char* tab = (unsigned char*)d_ws + TAB_OFF_BYTES;

  // 1. fused front: presplit kv + layernorm + bucket table (one launch)
  fused_pre<<<1096, 256, 0, stream>>>(kv, AKVH, AKVL, rel_emb, ln_g, ln_b, rebuf, tab);
  // 2. positional projections (MFMA split-bf16)
  gemm_pos<<<dim3(16, 1, 2), 256, 0, stream>>>(rebuf, Wpk, bpk, poskbuf, Wpq, bpq, posqbuf);
  // 3. Q/K/V projections fused (L2-aware XCD tiling)
  gemm_split<<<dim3(16, 16, 3), 256, 0, stream>>>(
      query, AKVH, AKVL,  Wq, Wk, Wv,  bq, bk, bv,
      QH, QL, KH, KL, VTH, VTL, 1024);
  // 4. c2p / p2c via MFMA (z-fused, bf16 out, pre-scaled by 1/sqrt(128))
  relproj_mfma<<<dim3(4, 32, 2), 256, 0, stream>>>(
      QH, QL, KH, KL, poskbuf, posqbuf, c2pbuf, p2cbuf);
  // 5. MFMA flash attention (round-10 structure, 512 blocks, XCD-swizzled)
  attn_mfma<<<dim3(16, 32), 256, 0, stream>>>(QH, QL, KH, KL, VTH, VTL,
                                              c2pbuf, p2cbuf, amask, tab, CTXH, CTXL);
  // 6. output projection -> d_out (L2-aware XCD tiling)
  gemm_out<<<dim3(16, 32), 256, 0, stream>>>(CTXH, CTXL, Wo, bo, (float*)d_out);
}